// Round 7
// baseline (108.530 us; speedup 1.0000x reference)
//
#include <hip/hip_runtime.h>
#include <cstdint>
#include <cstddef>

// Sparse submanifold 3x3x3 conv, C_in=C_out=64, fp32. SHAPE=(256,256,256), BS=2
// -> packed key = (b<<24)|(x<<16)|(y<<8)|z  == linear voxel id (25 bits).
//
// center tap (k=13): dense 200K x 64 @ 64 x 64 GEMM via bf16 MFMA
// (16x16x32), W13 pre-packed into fragment order. Non-center taps: BITMAP
// SWEEP probe — one thread per bitmap word; zero words exit after one
// coalesced load; nonzero words read 4 neighbor-row words at fixed strides
// (coalesced across lanes) and form hit masks by register shifts; only
// actual hits (~31K) resolve original indices via the u64 hash table.
// Pairs bucketed by tap k into 27 regions; conv_pairs assigns 48 blocks
// per region (W[k] L1-resident), fp32 FMA + atomics.
//
// R1: 13 offsets (mutual symmetry), batched MLP probe.
// R2: FAILED — 12.5K same-address reservation atomics = serialized chain.
// R3: conv_pairs region-loop collapsed parallelism (occ 7%).
// R4: per-k bucketing + static region/block conv_pairs; probe 43.7us top.
// R5: FAILED — probe+center fusion: both vmem-pipe-bound, superadditive
//     (cache thrash). Don't mix streaming with latency-sensitive cached.
// R6: site-driven bitmap probe ~26us (delta-inferred), not predicted 14:
//     random site order -> 1.15M random requests thrash per-XCD L2
//     (bitmap 4.2MB + streams > 4MiB). Also: harness re-poisons the 256MiB
//     ws every iter (~40us fill, top-5) — fixed tax; our budget is ~60us.
// R7(this): bitmap-DRIVEN sweep: word-centric, coalesced stencil reads,
//     divergent loads only for the ~62K hit lookups. Probe ~26 -> ~5-8us.

typedef __attribute__((ext_vector_type(8))) short bf16x8;
typedef __attribute__((ext_vector_type(4))) float f32x4;

static constexpr unsigned long long EMPTY64 = ~0ull;
static constexpr int LCAP = 512;      // LDS-staged pairs per block (expected ~16)
static constexpr unsigned NREGION = 27;  // pair regions, indexed by tap k
static constexpr unsigned CPAD = 16;     // counter padding (uints): 64B apart
static constexpr int PB = 48;         // conv_pairs blocks per region
static constexpr int NBWORDS = (2 << 24) >> 5;   // bitmap u32 words (BS=2): 1M

__device__ __forceinline__ unsigned hash_mix(unsigned key) {
    unsigned h = key * 0x9E3779B1u;
    h ^= h >> 15;
    return h;
}

__device__ __forceinline__ unsigned short f2bf(float x) {  // RNE fp32->bf16
    unsigned u = __builtin_bit_cast(unsigned, x);
    return (unsigned short)((u + 0x7FFFu + ((u >> 16) & 1u)) >> 16);
}

// hash lookup: key -> original site index (present by construction; returns
// ~0u defensively if not found).
__device__ __forceinline__ unsigned lookup_idx(
    const unsigned long long* __restrict__ table, unsigned mask, unsigned key)
{
    unsigned s = hash_mix(key) & mask;
    unsigned long long e = table[s];
    while ((unsigned)e != key) {
        if (e == EMPTY64) return 0xFFFFFFFFu;
        s = (s + 1) & mask;
        e = table[s];
    }
    return (unsigned)(e >> 32);
}

// init: clear hash table (u64), clear bitmap, zero padded region counters,
// build W13 bf16 fragment table. wfrag entry e = (ks*4 + nt)*64 + lane,
// elem j = bf16(W13[ks*32+(lane>>4)*8+j][nt*16+(lane&15)]).
__global__ void init_table_kernel(unsigned long long* __restrict__ table,
                                  int nslots, unsigned* __restrict__ bitmap,
                                  int nbwords, unsigned* __restrict__ cnts,
                                  const float* __restrict__ weight,
                                  unsigned short* __restrict__ wfrag) {
    int i = blockIdx.x * blockDim.x + threadIdx.x;
    if (i < nslots) table[i] = EMPTY64;
    if (i < nbwords) bitmap[i] = 0u;
    if (i < 512) {
        cnts[i] = 0u;   // covers NREGION*CPAD = 432 padded counters
        const int lane = i & 63, nt = (i >> 6) & 3, ks = i >> 8;
        const float* __restrict__ w13 = weight + 13 * 4096;
        #pragma unroll
        for (int j = 0; j < 8; ++j) {
            const int k = ks * 32 + (lane >> 4) * 8 + j;
            const int n = nt * 16 + (lane & 15);
            wfrag[(size_t)i * 8 + j] = f2bf(w13[k * 64 + n]);
        }
    }
}

// insert into hash table (u64 key|idx entry) AND set occupancy bit.
__global__ void insert_kernel(const int4* __restrict__ coords, int n,
                              unsigned long long* __restrict__ table,
                              unsigned mask, unsigned* __restrict__ bitmap) {
    int i = blockIdx.x * blockDim.x + threadIdx.x;
    if (i >= n) return;
    const int4 c = coords[i];   // (b, x, y, z)
    const unsigned key = ((unsigned)c.x << 24) | ((unsigned)c.y << 16) |
                         ((unsigned)c.z << 8) | (unsigned)c.w;
    atomicOr(&bitmap[key >> 5], 1u << (key & 31));
    const unsigned long long entry =
        (unsigned long long)key | ((unsigned long long)(unsigned)i << 32);
    unsigned s = hash_mix(key) & mask;
    while (atomicCAS((unsigned long long*)&table[s], EMPTY64, entry) !=
           EMPTY64)
        s = (s + 1) & mask;   // coords unique -> no duplicate keys
}

// Bitmap-driven sweep. One thread per u32 bitmap word w (layout: w =
// (b<<19)|(x<<11)|(y<<3)|(z>>5)). Zero word -> exit (83%). Nonzero: read
// the 4 neighbor-row words covering the 13 symmetric offsets k<13
// (g0..g2: x-1,y-1..y+1 at w-2056/-2048/-2040; g3: y-1 at w-8; g4: own
// word), all coalesced across lanes. dz=+-1 via shifts; word-edge carry
// words loaded only when cw bit0/bit31 set (<1%). k = 3*g + (dz+1).
// Each hit resolves (site, nbi) via hash table, emits (site,k,nbi) AND
// mirror (nbi,26-k,site) into LDS; flush bucketed by tap k.
__global__ __launch_bounds__(256) void probe_sweep_kernel(
    const unsigned long long* __restrict__ table, unsigned mask,
    const unsigned* __restrict__ bitmap, int nwords,
    unsigned* __restrict__ cnts, uint2* __restrict__ pairs, unsigned rcap)
{
    __shared__ unsigned lcnt;
    __shared__ unsigned lk[32], lkb[32], lkp[32];
    __shared__ uint2 lbuf[LCAP];
    if (threadIdx.x == 0) lcnt = 0u;
    if (threadIdx.x < 32) lk[threadIdx.x] = 0u;
    __syncthreads();

    const int w = blockIdx.x * blockDim.x + threadIdx.x;
    if (w < nwords) {
        const unsigned cw = bitmap[w];
        if (cw) {
            const int zw = w & 7;
            const int y = (w >> 3) & 255;
            const int x = (w >> 11) & 255;
            const bool needlo = (zw > 0) && (cw & 1u);
            const bool needhi = (zw < 7) && (cw >> 31);

            // neighbor rows (coalesced: consecutive lanes -> consecutive addrs)
            unsigned R[4], Rlo[4], Rhi[4];
            #pragma unroll
            for (int g = 0; g < 4; ++g) {
                const int off = (g == 0) ? -2056 : (g == 1) ? -2048
                              : (g == 2) ? -2040 : -8;
                const bool vg = (g == 0) ? (x > 0 && y > 0)
                              : (g == 1) ? (x > 0)
                              : (g == 2) ? (x > 0 && y < 255)
                              : (y > 0);
                const int bwi = w + off;
                R[g]   = vg ? bitmap[bwi] : 0u;
                Rlo[g] = (vg && needlo) ? bitmap[bwi - 1] : 0u;
                Rhi[g] = (vg && needhi) ? bitmap[bwi + 1] : 0u;
            }
            const unsigned Rl4 = needlo ? bitmap[w - 1] : 0u;

            unsigned memo_key = 0xFFFFFFFFu, memo_site = 0u;
            #pragma unroll
            for (int g = 0; g < 5; ++g) {
                const int dx = (g < 3) ? -1 : 0;
                const int dy = (g < 3) ? (g - 1) : ((g == 3) ? -1 : 0);
                unsigned pm[3];
                if (g < 4) {
                    pm[0] = cw & ((R[g] << 1) | (Rlo[g] >> 31));
                    pm[1] = cw & R[g];
                    pm[2] = cw & ((R[g] >> 1) | (Rhi[g] << 31));
                } else {
                    pm[0] = cw & ((cw << 1) | (Rl4 >> 31));
                    pm[1] = 0u;
                    pm[2] = 0u;
                }
                #pragma unroll
                for (int d = 0; d < 3; ++d) {
                    unsigned m = pm[d];
                    const int k = 3 * g + d;
                    const int duv = (dx << 16) + (dy << 8) + (d - 1);
                    while (m) {
                        const int p = __ffs(m) - 1;
                        m &= m - 1;
                        const unsigned vkey = ((unsigned)w << 5) | (unsigned)p;
                        const unsigned ukey = (unsigned)((int)vkey + duv);
                        unsigned site;
                        if (vkey == memo_key) site = memo_site;
                        else {
                            site = lookup_idx(table, mask, vkey);
                            memo_key = vkey; memo_site = site;
                        }
                        const unsigned nbi = lookup_idx(table, mask, ukey);
                        if (site == 0xFFFFFFFFu || nbi == 0xFFFFFFFFu)
                            continue;   // defensive (can't happen)
                        const uint2 p0 = make_uint2(
                            site | ((unsigned)k << 18), nbi);
                        const uint2 p1 = make_uint2(
                            nbi | ((unsigned)(26 - k) << 18), site);
                        const unsigned li = atomicAdd(&lcnt, 2u);
                        if (li + 1 < (unsigned)LCAP) {  // li even, LCAP even
                            lbuf[li] = p0;
                            lbuf[li + 1] = p1;
                        } else {                         // statistically ~never
                            const unsigned g0 =
                                atomicAdd(&cnts[k * CPAD], 1u);
                            if (g0 < rcap) pairs[(size_t)k * rcap + g0] = p0;
                            const unsigned g1 =
                                atomicAdd(&cnts[(26 - k) * CPAD], 1u);
                            if (g1 < rcap)
                                pairs[(size_t)(26 - k) * rcap + g1] = p1;
                        }
                    }
                }
            }
        }
    }

    __syncthreads();
    const unsigned nloc = lcnt < (unsigned)LCAP ? lcnt : (unsigned)LCAP;
    // per-k histogram of staged pairs
    for (unsigned i = threadIdx.x; i < nloc; i += blockDim.x)
        atomicAdd(&lk[lbuf[i].x >> 18], 1u);
    __syncthreads();
    // one padded global reservation per nonempty k
    if (threadIdx.x < NREGION) {
        const unsigned c = lk[threadIdx.x];
        lkb[threadIdx.x] = c ? atomicAdd(&cnts[threadIdx.x * CPAD], c) : 0u;
        lkp[threadIdx.x] = 0u;
    }
    __syncthreads();
    // scatter into per-k regions
    for (unsigned i = threadIdx.x; i < nloc; i += blockDim.x) {
        const uint2 e = lbuf[i];
        const unsigned kk = e.x >> 18;
        const unsigned pos = atomicAdd(&lkp[kk], 1u);
        const unsigned idx = lkb[kk] + pos;
        if (idx < rcap) pairs[(size_t)kk * rcap + idx] = e;
    }
}

// Dense center GEMM via MFMA: out = bias + feats @ W13.
// One wave per 16 sites x 64 oc. A: row=lane&15, k=(lane>>4)*8+j (+ks*32).
// B pre-packed in wfrag. C/D: col=lane&15, row=(lane>>4)*4+reg.
__global__ __launch_bounds__(256) void conv_center_mfma(
    const float* __restrict__ feats, const unsigned short* __restrict__ wfrag,
    const float* __restrict__ bias, float* __restrict__ out, int n)
{
    const int lane = threadIdx.x & 63;
    const int wid = blockIdx.x * (blockDim.x >> 6) + (threadIdx.x >> 6);
    const int s0 = wid * 16;
    if (s0 >= n) return;

    // B fragments: 2 ksteps x 4 ntiles, 16B per lane each
    bf16x8 bfrag[2][4];
    #pragma unroll
    for (int ks = 0; ks < 2; ++ks)
        #pragma unroll
        for (int nt = 0; nt < 4; ++nt)
            bfrag[ks][nt] = *reinterpret_cast<const bf16x8*>(
                wfrag + ((size_t)((ks * 4 + nt) * 64 + lane)) * 8);

    const int arow = s0 + (lane & 15);
    const bool vrow = arow < n;
    const float* __restrict__ fbase =
        feats + (size_t)(vrow ? arow : 0) * 64 + (lane >> 4) * 8;

    f32x4 acc[4] = {{0.f, 0.f, 0.f, 0.f}, {0.f, 0.f, 0.f, 0.f},
                    {0.f, 0.f, 0.f, 0.f}, {0.f, 0.f, 0.f, 0.f}};

    #pragma unroll
    for (int ks = 0; ks < 2; ++ks) {
        const f32x4 flo = *reinterpret_cast<const f32x4*>(fbase + ks * 32);
        const f32x4 fhi = *reinterpret_cast<const f32x4*>(fbase + ks * 32 + 4);
        bf16x8 afrag;
        afrag[0] = (short)f2bf(flo.x); afrag[1] = (short)f2bf(flo.y);
        afrag[2] = (short)f2bf(flo.z); afrag[3] = (short)f2bf(flo.w);
        afrag[4] = (short)f2bf(fhi.x); afrag[5] = (short)f2bf(fhi.y);
        afrag[6] = (short)f2bf(fhi.z); afrag[7] = (short)f2bf(fhi.w);
        #pragma unroll
        for (int nt = 0; nt < 4; ++nt)
            acc[nt] = __builtin_amdgcn_mfma_f32_16x16x32_bf16(
                afrag, bfrag[ks][nt], acc[nt], 0, 0, 0);
    }

    const int crow0 = s0 + (lane >> 4) * 4;
    const int col = lane & 15;
    #pragma unroll
    for (int nt = 0; nt < 4; ++nt) {
        const float bv = bias[nt * 16 + col];
        #pragma unroll
        for (int r = 0; r < 4; ++r) {
            const int sr = crow0 + r;
            if (sr < n)
                out[(size_t)sr * 64 + nt * 16 + col] = acc[nt][r] + bv;
        }
    }
}

// 48 blocks per tap region; one wave per pair (grid-stride within region).
// All waves of a block stream the same 16KB W[k] -> L1-resident after the
// first pair. fp32 FMA + atomics (bit-identical math to R0's pairs path).
__global__ __launch_bounds__(256) void conv_pairs_kernel(
    const float* __restrict__ feats, const float* __restrict__ weight,
    const uint2* __restrict__ pairs, const unsigned* __restrict__ cnts,
    unsigned rcap, float* __restrict__ out)
{
    const int lane = threadIdx.x & 63;
    int r = blockIdx.x / PB;
    r += (r >= 13);                     // taps 0..12,14..26
    unsigned cnt = cnts[r * CPAD];
    if (cnt > rcap) cnt = rcap;
    if (cnt == 0) return;
    const uint2* __restrict__ rp = pairs + (size_t)r * rcap;
    const float* __restrict__ wk = weight + (size_t)r * 4096;
    const unsigned wloc = (blockIdx.x % PB) * 4 + (threadIdx.x >> 6);
    for (unsigned p = wloc; p < cnt; p += (unsigned)(PB * 4)) {
        const uint2 pr = rp[p];
        const unsigned site = pr.x & 0x3FFFFu;
        const unsigned nbi = pr.y;
        const float4* __restrict__ fr =
            reinterpret_cast<const float4*>(feats + (size_t)nbi * 64);
        float a0 = 0.f, a1 = 0.f, a2 = 0.f, a3 = 0.f;
        #pragma unroll
        for (int q = 0; q < 16; ++q) {
            const float4 f = fr[q];
            a0 = fmaf(f.x, wk[(4 * q + 0) * 64 + lane], a0);
            a1 = fmaf(f.y, wk[(4 * q + 1) * 64 + lane], a1);
            a2 = fmaf(f.z, wk[(4 * q + 2) * 64 + lane], a2);
            a3 = fmaf(f.w, wk[(4 * q + 3) * 64 + lane], a3);
        }
        atomicAdd(&out[(size_t)site * 64 + lane], (a0 + a1) + (a2 + a3));
    }
}

extern "C" void kernel_launch(void* const* d_in, const int* in_sizes, int n_in,
                              void* d_out, int out_size, void* d_ws, size_t ws_size,
                              hipStream_t stream) {
    const float* feats  = (const float*)d_in[0];   // (N, 64)
    const int4*  coords = (const int4*)d_in[1];    // (N, 4)
    const float* weight = (const float*)d_in[2];   // (27, 64, 64)
    const float* bias   = (const float*)d_in[3];   // (64,)
    float* out = (float*)d_out;

    const int n = in_sizes[1] / 4;

    // ws layout: table (nslots u64) | bitmap (NBWORDS+4 u32) |
    //            cnts (2KB = 27 padded counters) | wfrag (8KB) | pairs
    const bool big = ws_size >= ((size_t)16 << 20);
    const int nslots = big ? (1 << 19) : (1 << 18);
    const unsigned mask = (unsigned)(nslots - 1);
    const int nbclear = NBWORDS + 4;               // +pad for edge reads
    unsigned long long* table = (unsigned long long*)d_ws;
    unsigned* bitmap = (unsigned*)(table + nslots);
    unsigned* cnts = bitmap + nbclear;
    unsigned short* wfrag = (unsigned short*)((char*)cnts + 2048);
    uint2* pairs = (uint2*)((char*)wfrag + 8192);
    const size_t used = (size_t)nslots * 8 + (size_t)nbclear * 4 + 2048 + 8192;
    size_t cap_sz = (ws_size > used) ? (ws_size - used) / sizeof(uint2) : 0;
    if (cap_sz > (size_t)(4 << 20)) cap_sz = (size_t)(4 << 20);
    const unsigned rcap = (unsigned)(cap_sz / NREGION);

    {
        const int work = (nslots > nbclear) ? nslots : nbclear;
        int blocks = (work + 255) / 256;
        init_table_kernel<<<blocks, 256, 0, stream>>>(table, nslots, bitmap,
                                                      nbclear, cnts, weight,
                                                      wfrag);
    }
    {
        int blocks = (n + 255) / 256;
        insert_kernel<<<blocks, 256, 0, stream>>>(coords, n, table, mask,
                                                  bitmap);
    }
    {
        int blocks = (NBWORDS + 255) / 256;   // one thread per bitmap word
        probe_sweep_kernel<<<blocks, 256, 0, stream>>>(table, mask, bitmap,
                                                       NBWORDS, cnts, pairs,
                                                       rcap);
    }
    {
        int waves = (n + 15) / 16;
        int blocks = (waves + 3) / 4;
        conv_center_mfma<<<blocks, 256, 0, stream>>>(feats, wfrag, bias, out, n);
    }
    {
        conv_pairs_kernel<<<26 * PB, 256, 0, stream>>>(feats, weight, pairs,
                                                       cnts, rcap, out);
    }
}

// Round 8
// 97.763 us; speedup vs baseline: 1.1101x; 1.1101x over previous
//
#include <hip/hip_runtime.h>
#include <cstdint>
#include <cstddef>

// Sparse submanifold 3x3x3 conv, C_in=C_out=64, fp32. SHAPE=(256,256,256), BS=2
// -> packed key = (b<<24)|(x<<16)|(y<<8)|z  == linear voxel id (25 bits).
//
// center tap (k=13): dense 200K x 64 @ 64 x 64 GEMM via bf16 MFMA
// (16x16x32), W13 pre-packed into fragment order. Non-center taps: per-site
// probe against a 4.2MB occupancy bitmap tiled as 4y x 8z PATCH WORDS
// (word=(b,x,y>>2,z>>3), bit=(y&3)*8+(z&7)) — common case needs only TWO
// word loads for the whole 13-offset stencil (x-1 patch + own patch).
// Hits (~31K) resolve neighbor index via u64 hash table (key|idx<<32).
// Pairs bucketed by tap k into 27 regions; conv_pairs 48 blocks/region
// (W[k] L1-resident), fp32 FMA + atomics.
//
// R1: 13 offsets (mutual symmetry), batched MLP probe.
// R2: FAILED — 12.5K same-address reservation atomics = serialized chain.
// R3: conv_pairs region-loop collapsed parallelism (occ 7%).
// R4: per-k bucketing + static region/block conv_pairs; probe 43.7us top.
// R5: FAILED — probe+center fusion: both vmem-pipe-bound, superadditive.
// R6: site-driven z-run bitmap probe: ~26us = 200K x 5.3 divergent word
//     requests @ ~15cyc/req (model matches R0/R1/R4/R5). Total 99.4.
//     Harness re-poisons 256MiB ws every iter (~40us fill) — fixed tax.
// R7: FAILED — bitmap-driven sweep ~35us despite tiny coalesced request
//     count: 15 inlined divergent while-loops of dependent hash walks pay
//     latency on nearly every wave. Reverted.
// R8(this): R6 base, bitmap re-tiled to 4y x 8z patches: requests/site
//     5.3 -> ~3.2 (2 in the 37% interior case), y/z bounds handled by
//     load validity (no zmask). Predict probe ~16us, total ~90us.

typedef __attribute__((ext_vector_type(8))) short bf16x8;
typedef __attribute__((ext_vector_type(4))) float f32x4;

static constexpr unsigned long long EMPTY64 = ~0ull;
static constexpr int LCAP = 512;      // LDS-staged pairs per block (mean ~160)
static constexpr unsigned NREGION = 27;  // pair regions, indexed by tap k
static constexpr unsigned CPAD = 16;     // counter padding (uints): 64B apart
static constexpr int PB = 48;         // conv_pairs blocks per region
static constexpr int NBWORDS = 1 << 20;  // patch words: 2*256*64*32 = 1M

__device__ __forceinline__ unsigned hash_mix(unsigned key) {
    unsigned h = key * 0x9E3779B1u;
    h ^= h >> 15;
    return h;
}

__device__ __forceinline__ unsigned short f2bf(float x) {  // RNE fp32->bf16
    unsigned u = __builtin_bit_cast(unsigned, x);
    return (unsigned short)((u + 0x7FFFu + ((u >> 16) & 1u)) >> 16);
}

// init: clear hash table (u64), clear bitmap, zero padded region counters,
// build W13 bf16 fragment table. wfrag entry e = (ks*4 + nt)*64 + lane,
// elem j = bf16(W13[ks*32+(lane>>4)*8+j][nt*16+(lane&15)]).
__global__ void init_table_kernel(unsigned long long* __restrict__ table,
                                  int nslots, unsigned* __restrict__ bitmap,
                                  int nbwords, unsigned* __restrict__ cnts,
                                  const float* __restrict__ weight,
                                  unsigned short* __restrict__ wfrag) {
    int i = blockIdx.x * blockDim.x + threadIdx.x;
    if (i < nslots) table[i] = EMPTY64;
    if (i < nbwords) bitmap[i] = 0u;
    if (i < 512) {
        cnts[i] = 0u;   // covers NREGION*CPAD = 432 padded counters
        const int lane = i & 63, nt = (i >> 6) & 3, ks = i >> 8;
        const float* __restrict__ w13 = weight + 13 * 4096;
        #pragma unroll
        for (int j = 0; j < 8; ++j) {
            const int k = ks * 32 + (lane >> 4) * 8 + j;
            const int n = nt * 16 + (lane & 15);
            wfrag[(size_t)i * 8 + j] = f2bf(w13[k * 64 + n]);
        }
    }
}

// insert into hash table (u64 key|idx entry) AND set patch-bitmap bit.
__global__ void insert_kernel(const int4* __restrict__ coords, int n,
                              unsigned long long* __restrict__ table,
                              unsigned mask, unsigned* __restrict__ bitmap) {
    int i = blockIdx.x * blockDim.x + threadIdx.x;
    if (i >= n) return;
    const int4 c = coords[i];   // (b, x, y, z)
    const unsigned key = ((unsigned)c.x << 24) | ((unsigned)c.y << 16) |
                         ((unsigned)c.z << 8) | (unsigned)c.w;
    const unsigned w = ((((unsigned)c.x << 8) | (unsigned)c.y) << 11) |
                       (((unsigned)c.z >> 2) << 5) | ((unsigned)c.w >> 3);
    const unsigned bit = (((unsigned)c.z & 3u) << 3) | ((unsigned)c.w & 7u);
    atomicOr(&bitmap[w], 1u << bit);
    const unsigned long long entry =
        (unsigned long long)key | ((unsigned long long)(unsigned)i << 32);
    unsigned s = hash_mix(key) & mask;
    while (atomicCAS((unsigned long long*)&table[s], EMPTY64, entry) !=
           EMPTY64)
        s = (s + 1) & mask;   // coords unique -> no duplicate keys
}

// One thread per site. Patch-word existence test: word (b,x,yt,zt) holds a
// 4y x 8z occupancy tile (bit = (y&3)*8 + (z&7)). The 13 symmetric offsets
// k<13 need 5 rows: A=(x-1,y-1) B=(x-1,y) C=(x-1,y+1) [tri over z+-1],
// D=(x,y-1) [tri], E=(x,y) [z-1 bit only]. Common case (y&3 in {1,2},
// z&7 in {1..6}): 2 loads. y-tile/z-tile edges add exec-masked loads;
// out-of-volume tiles are simply not loaded (0 word -> 0 bits), so no
// boundary masks needed. Hits resolve nbi via hash table, emit
// (site,k,nbi) AND mirror (nbi,26-k,site) into LDS; flush bucketed by k.
__global__ __launch_bounds__(512) void probe_pairs_kernel(
    const int4* __restrict__ coords, int n,
    const unsigned long long* __restrict__ table, unsigned mask,
    const unsigned* __restrict__ bitmap,
    unsigned* __restrict__ cnts, uint2* __restrict__ pairs, unsigned rcap)
{
    __shared__ unsigned lcnt;
    __shared__ unsigned lk[32], lkb[32], lkp[32];
    __shared__ uint2 lbuf[LCAP];
    if (threadIdx.x == 0) lcnt = 0u;
    if (threadIdx.x < 32) lk[threadIdx.x] = 0u;
    __syncthreads();

    const int site = blockIdx.x * blockDim.x + threadIdx.x;
    if (site < n) {
        const int4 c = coords[site];   // (b, x, y, z)
        const int b = c.x, x = c.y, y = c.z, z = c.w;
        const int r = y & 3, yt = y >> 2;
        const int s = z & 7, zt = z >> 3;
        const bool redge = (r == 0) || (r == 3);
        const int yta = (r == 0) ? yt - 1 : yt + 1;   // aux y-tile
        const bool vya = (r == 0) ? (y > 0) : (y < 255);
        const bool zl = (s == 0) && (z > 0);          // need z-1 from prev tile
        const bool zh = (s == 7) && (z < 255);        // need z+1 from next tile
        const bool vxm = (x > 0);
        const int xm = x - 1;

        #define BWORD(xx, ytt, ztt) \
            bitmap[((((unsigned)b << 8) | (unsigned)(xx)) << 11) | \
                   ((unsigned)(ytt) << 5) | (unsigned)(ztt)]

        // phase 1: all patch words in flight (independent loads)
        const unsigned Pm  = vxm ? BWORD(xm, yt, zt) : 0u;
        const unsigned Pa  = (vxm && redge && vya) ? BWORD(xm, yta, zt) : 0u;
        const unsigned Pml = (vxm && zl) ? BWORD(xm, yt, zt - 1) : 0u;
        const unsigned Pal = (vxm && redge && vya && zl)
                                 ? BWORD(xm, yta, zt - 1) : 0u;
        const unsigned Pmh = (vxm && zh) ? BWORD(xm, yt, zt + 1) : 0u;
        const unsigned Pah = (vxm && redge && vya && zh)
                                 ? BWORD(xm, yta, zt + 1) : 0u;
        const unsigned Qm  = BWORD(x, yt, zt);
        const bool qa = (r == 0) && (y > 0);
        const unsigned Qa  = qa ? BWORD(x, yt - 1, zt) : 0u;
        const unsigned Qml = zl ? BWORD(x, yt, zt - 1) : 0u;
        const unsigned Qal = (qa && zl) ? BWORD(x, yt - 1, zt - 1) : 0u;
        const unsigned Qmh = zh ? BWORD(x, yt, zt + 1) : 0u;
        const unsigned Qah = (qa && zh) ? BWORD(x, yt - 1, zt + 1) : 0u;
        #undef BWORD

        // phase 2: assemble 5 tri/bit masks
        const int rm1 = (r == 0) ? 3 : r - 1;    // byte idx of row y-1
        const int rp1 = (r == 3) ? 0 : r + 1;    // byte idx of row y+1
        const unsigned PA  = (r == 0) ? Pa : Pm;
        const unsigned PAl = (r == 0) ? Pal : Pml;
        const unsigned PAh = (r == 0) ? Pah : Pmh;
        const unsigned PC  = (r == 3) ? Pa : Pm;
        const unsigned PCl = (r == 3) ? Pal : Pml;
        const unsigned PCh = (r == 3) ? Pah : Pmh;
        const unsigned QA  = (r == 0) ? Qa : Qm;
        const unsigned QAl = (r == 0) ? Qal : Qml;
        const unsigned QAh = (r == 0) ? Qah : Qmh;

        #define ROWB(W, rr) (((W) >> ((rr) * 8)) & 0xFFu)
        unsigned triA, triB, triC, triD, bitE;
        {
            const unsigned cA = ROWB(PA, rm1), cB = ROWB(Pm, r),
                           cC = ROWB(PC, rp1), cD = ROWB(QA, rm1),
                           cE = ROWB(Qm, r);
            if (s == 0) {
                triA = ((cA & 3u) << 1) | (ROWB(PAl, rm1) >> 7);
                triB = ((cB & 3u) << 1) | (ROWB(Pml, r)   >> 7);
                triC = ((cC & 3u) << 1) | (ROWB(PCl, rp1) >> 7);
                triD = ((cD & 3u) << 1) | (ROWB(QAl, rm1) >> 7);
                bitE = ROWB(Qml, r) >> 7;
            } else if (s == 7) {
                triA = ((cA >> 6) & 3u) | ((ROWB(PAh, rm1) & 1u) << 2);
                triB = ((cB >> 6) & 3u) | ((ROWB(Pmh, r)   & 1u) << 2);
                triC = ((cC >> 6) & 3u) | ((ROWB(PCh, rp1) & 1u) << 2);
                triD = ((cD >> 6) & 3u) | ((ROWB(QAh, rm1) & 1u) << 2);
                bitE = (cE >> 6) & 1u;
            } else {
                triA = (cA >> (s - 1)) & 7u;
                triB = (cB >> (s - 1)) & 7u;
                triC = (cC >> (s - 1)) & 7u;
                triD = (cD >> (s - 1)) & 7u;
                bitE = (cE >> (s - 1)) & 1u;
            }
        }
        #undef ROWB
        unsigned hitm = triA | (triB << 3) | (triC << 6) | (triD << 9) |
                        (bitE << 12);

        // phase 3: resolve hits via hash table (present by construction)
        while (hitm) {
            const int bb = __ffs(hitm) - 1;
            hitm &= hitm - 1;
            const int g = bb / 3, d = bb % 3;       // k = 3g+d, dz = d-1
            const int dx = (g < 3) ? -1 : 0;
            const int dy = (g < 3) ? (g - 1) : ((g == 3) ? -1 : 0);
            const int k = 3 * g + d;
            const unsigned key = ((unsigned)b << 24) |
                                 ((unsigned)(x + dx) << 16) |
                                 ((unsigned)(y + dy) << 8) |
                                 (unsigned)(z + d - 1);
            unsigned sl = hash_mix(key) & mask;
            unsigned long long e = table[sl];
            while (e != EMPTY64 && (unsigned)e != key) {
                sl = (sl + 1) & mask;
                e = table[sl];
            }
            if (e == EMPTY64) continue;             // defensive (can't happen)
            const unsigned nbi = (unsigned)(e >> 32);
            const uint2 p0 = make_uint2((unsigned)site | ((unsigned)k << 18),
                                        nbi);
            const uint2 p1 = make_uint2(nbi | ((unsigned)(26 - k) << 18),
                                        (unsigned)site);
            const unsigned li = atomicAdd(&lcnt, 2u);
            if (li + 1 < (unsigned)LCAP) {          // li even, LCAP even
                lbuf[li] = p0;
                lbuf[li + 1] = p1;
            } else {                                 // statistically ~never
                const unsigned g0 = atomicAdd(&cnts[k * CPAD], 1u);
                if (g0 < rcap) pairs[(size_t)k * rcap + g0] = p0;
                const unsigned g1 = atomicAdd(&cnts[(26 - k) * CPAD], 1u);
                if (g1 < rcap) pairs[(size_t)(26 - k) * rcap + g1] = p1;
            }
        }
    }

    __syncthreads();
    const unsigned nloc = lcnt < (unsigned)LCAP ? lcnt : (unsigned)LCAP;
    // per-k histogram of staged pairs
    for (unsigned i = threadIdx.x; i < nloc; i += blockDim.x)
        atomicAdd(&lk[lbuf[i].x >> 18], 1u);
    __syncthreads();
    // one padded global reservation per nonempty k
    if (threadIdx.x < NREGION) {
        const unsigned c = lk[threadIdx.x];
        lkb[threadIdx.x] = c ? atomicAdd(&cnts[threadIdx.x * CPAD], c) : 0u;
        lkp[threadIdx.x] = 0u;
    }
    __syncthreads();
    // scatter into per-k regions
    for (unsigned i = threadIdx.x; i < nloc; i += blockDim.x) {
        const uint2 e = lbuf[i];
        const unsigned kk = e.x >> 18;
        const unsigned pos = atomicAdd(&lkp[kk], 1u);
        const unsigned idx = lkb[kk] + pos;
        if (idx < rcap) pairs[(size_t)kk * rcap + idx] = e;
    }
}

// Dense center GEMM via MFMA: out = bias + feats @ W13.
// One wave per 16 sites x 64 oc. A: row=lane&15, k=(lane>>4)*8+j (+ks*32).
// B pre-packed in wfrag. C/D: col=lane&15, row=(lane>>4)*4+reg.
__global__ __launch_bounds__(256) void conv_center_mfma(
    const float* __restrict__ feats, const unsigned short* __restrict__ wfrag,
    const float* __restrict__ bias, float* __restrict__ out, int n)
{
    const int lane = threadIdx.x & 63;
    const int wid = blockIdx.x * (blockDim.x >> 6) + (threadIdx.x >> 6);
    const int s0 = wid * 16;
    if (s0 >= n) return;

    // B fragments: 2 ksteps x 4 ntiles, 16B per lane each
    bf16x8 bfrag[2][4];
    #pragma unroll
    for (int ks = 0; ks < 2; ++ks)
        #pragma unroll
        for (int nt = 0; nt < 4; ++nt)
            bfrag[ks][nt] = *reinterpret_cast<const bf16x8*>(
                wfrag + ((size_t)((ks * 4 + nt) * 64 + lane)) * 8);

    const int arow = s0 + (lane & 15);
    const bool vrow = arow < n;
    const float* __restrict__ fbase =
        feats + (size_t)(vrow ? arow : 0) * 64 + (lane >> 4) * 8;

    f32x4 acc[4] = {{0.f, 0.f, 0.f, 0.f}, {0.f, 0.f, 0.f, 0.f},
                    {0.f, 0.f, 0.f, 0.f}, {0.f, 0.f, 0.f, 0.f}};

    #pragma unroll
    for (int ks = 0; ks < 2; ++ks) {
        const f32x4 flo = *reinterpret_cast<const f32x4*>(fbase + ks * 32);
        const f32x4 fhi = *reinterpret_cast<const f32x4*>(fbase + ks * 32 + 4);
        bf16x8 afrag;
        afrag[0] = (short)f2bf(flo.x); afrag[1] = (short)f2bf(flo.y);
        afrag[2] = (short)f2bf(flo.z); afrag[3] = (short)f2bf(flo.w);
        afrag[4] = (short)f2bf(fhi.x); afrag[5] = (short)f2bf(fhi.y);
        afrag[6] = (short)f2bf(fhi.z); afrag[7] = (short)f2bf(fhi.w);
        #pragma unroll
        for (int nt = 0; nt < 4; ++nt)
            acc[nt] = __builtin_amdgcn_mfma_f32_16x16x32_bf16(
                afrag, bfrag[ks][nt], acc[nt], 0, 0, 0);
    }

    const int crow0 = s0 + (lane >> 4) * 4;
    const int col = lane & 15;
    #pragma unroll
    for (int nt = 0; nt < 4; ++nt) {
        const float bv = bias[nt * 16 + col];
        #pragma unroll
        for (int r = 0; r < 4; ++r) {
            const int sr = crow0 + r;
            if (sr < n)
                out[(size_t)sr * 64 + nt * 16 + col] = acc[nt][r] + bv;
        }
    }
}

// 48 blocks per tap region; one wave per pair (grid-stride within region).
// All waves of a block stream the same 16KB W[k] -> L1-resident after the
// first pair. fp32 FMA + atomics (bit-identical math to R0's pairs path).
__global__ __launch_bounds__(256) void conv_pairs_kernel(
    const float* __restrict__ feats, const float* __restrict__ weight,
    const uint2* __restrict__ pairs, const unsigned* __restrict__ cnts,
    unsigned rcap, float* __restrict__ out)
{
    const int lane = threadIdx.x & 63;
    int r = blockIdx.x / PB;
    r += (r >= 13);                     // taps 0..12,14..26
    unsigned cnt = cnts[r * CPAD];
    if (cnt > rcap) cnt = rcap;
    if (cnt == 0) return;
    const uint2* __restrict__ rp = pairs + (size_t)r * rcap;
    const float* __restrict__ wk = weight + (size_t)r * 4096;
    const unsigned wloc = (blockIdx.x % PB) * 4 + (threadIdx.x >> 6);
    for (unsigned p = wloc; p < cnt; p += (unsigned)(PB * 4)) {
        const uint2 pr = rp[p];
        const unsigned site = pr.x & 0x3FFFFu;
        const unsigned nbi = pr.y;
        const float4* __restrict__ fr =
            reinterpret_cast<const float4*>(feats + (size_t)nbi * 64);
        float a0 = 0.f, a1 = 0.f, a2 = 0.f, a3 = 0.f;
        #pragma unroll
        for (int q = 0; q < 16; ++q) {
            const float4 f = fr[q];
            a0 = fmaf(f.x, wk[(4 * q + 0) * 64 + lane], a0);
            a1 = fmaf(f.y, wk[(4 * q + 1) * 64 + lane], a1);
            a2 = fmaf(f.z, wk[(4 * q + 2) * 64 + lane], a2);
            a3 = fmaf(f.w, wk[(4 * q + 3) * 64 + lane], a3);
        }
        atomicAdd(&out[(size_t)site * 64 + lane], (a0 + a1) + (a2 + a3));
    }
}

extern "C" void kernel_launch(void* const* d_in, const int* in_sizes, int n_in,
                              void* d_out, int out_size, void* d_ws, size_t ws_size,
                              hipStream_t stream) {
    const float* feats  = (const float*)d_in[0];   // (N, 64)
    const int4*  coords = (const int4*)d_in[1];    // (N, 4)
    const float* weight = (const float*)d_in[2];   // (27, 64, 64)
    const float* bias   = (const float*)d_in[3];   // (64,)
    float* out = (float*)d_out;

    const int n = in_sizes[1] / 4;

    // ws layout: table (nslots u64) | bitmap (NBWORDS+4 u32) |
    //            cnts (2KB = 27 padded counters) | wfrag (8KB) | pairs
    const bool big = ws_size >= ((size_t)16 << 20);
    const int nslots = big ? (1 << 19) : (1 << 18);
    const unsigned mask = (unsigned)(nslots - 1);
    const int nbclear = NBWORDS + 4;               // +pad (defensive)
    unsigned long long* table = (unsigned long long*)d_ws;
    unsigned* bitmap = (unsigned*)(table + nslots);
    unsigned* cnts = bitmap + nbclear;
    unsigned short* wfrag = (unsigned short*)((char*)cnts + 2048);
    uint2* pairs = (uint2*)((char*)wfrag + 8192);
    const size_t used = (size_t)nslots * 8 + (size_t)nbclear * 4 + 2048 + 8192;
    size_t cap_sz = (ws_size > used) ? (ws_size - used) / sizeof(uint2) : 0;
    if (cap_sz > (size_t)(4 << 20)) cap_sz = (size_t)(4 << 20);
    const unsigned rcap = (unsigned)(cap_sz / NREGION);

    {
        const int work = (nslots > nbclear) ? nslots : nbclear;
        int blocks = (work + 255) / 256;
        init_table_kernel<<<blocks, 256, 0, stream>>>(table, nslots, bitmap,
                                                      nbclear, cnts, weight,
                                                      wfrag);
    }
    {
        int blocks = (n + 255) / 256;
        insert_kernel<<<blocks, 256, 0, stream>>>(coords, n, table, mask,
                                                  bitmap);
    }
    {
        int blocks = (n + 511) / 512;   // 512 sites/block, 1 thread/site
        probe_pairs_kernel<<<blocks, 512, 0, stream>>>(coords, n, table, mask,
                                                       bitmap, cnts, pairs,
                                                       rcap);
    }
    {
        int waves = (n + 15) / 16;
        int blocks = (waves + 3) / 4;
        conv_center_mfma<<<blocks, 256, 0, stream>>>(feats, wfrag, bias, out, n);
    }
    {
        conv_pairs_kernel<<<26 * PB, 256, 0, stream>>>(feats, weight, pairs,
                                                       cnts, rcap, out);
    }
}

// Round 9
// 81.888 us; speedup vs baseline: 1.3254x; 1.1939x over previous
//
#include <hip/hip_runtime.h>
#include <cstdint>
#include <cstddef>

// Sparse submanifold 3x3x3 conv, C_in=C_out=64, fp32. SHAPE=(256,256,256), BS=2
// -> packed key = (b<<24)|(x<<16)|(y<<8)|z  == linear voxel id (25 bits).
//
// center tap (k=13): dense 200K x 64 @ 64 x 64 GEMM via bf16 MFMA
// (16x16x32), W13 pre-packed into fragment order. Non-center taps: per-site
// probe against a 4.2MB occupancy bitmap tiled as 4y x 8z PATCH WORDS
// (word=(b,x,y>>2,z>>3), bit=(y&3)*8+(z&7)); hits resolve the neighbor
// index via a DIRECT idx[] array (u32 per voxel, 128MB, never cleared —
// validity proven by the bitmap; ws is 256MiB and re-poisoned anyway).
// Pairs bucketed by tap k into 27 regions; conv_pairs 48 blocks/region
// (W[k] L1-resident), fp32 FMA + atomics.
//
// R1: 13 offsets (mutual symmetry, emit both directions per hit).
// R2: FAILED — 12.5K same-address reservation atomics = serialized chain.
// R3: conv_pairs region-loop collapsed parallelism (occ 7%).
// R4: per-k bucketing + static region/block conv_pairs; probe 43.7us top.
// R5: FAILED — probe+center fusion: both vmem-pipe-bound, superadditive.
// R6: site-driven bitmap probe (z-run words). Total 99.4. Fill tax: harness
//     re-poisons 256MiB ws every iter (~39.4us) — fixed, 40% of total.
// R7: FAILED — bitmap-driven sweep: divergent dependent hash-walk loops.
// R8: 4y x 8z patch retile: −1.6us only — request-count model REFUTED;
//     probe is actually small (~5-10us); remaining mass is front-end glue
//     (12MB init clear, insert CAS chains, serialized hit walks) + pairs.
// R9(this): hash table -> direct idx[key] (no clear, no CAS, 1-load
//     resolution); hit resolution restructured to batched exec-masked
//     loads (static unroll, rule #20) — one latency round-trip per wave.

typedef __attribute__((ext_vector_type(8))) short bf16x8;
typedef __attribute__((ext_vector_type(4))) float f32x4;

static constexpr int LCAP = 512;      // LDS-staged pairs per block (mean ~160)
static constexpr unsigned NREGION = 27;  // pair regions, indexed by tap k
static constexpr unsigned CPAD = 16;     // counter padding (uints): 64B apart
static constexpr int PB = 48;         // conv_pairs blocks per region
static constexpr int NBWORDS = 1 << 20;  // patch words: 2*256*64*32 = 1M
static constexpr size_t NVOX = (size_t)1 << 25;  // voxel ids (BS=2): 32M

__device__ __forceinline__ unsigned short f2bf(float x) {  // RNE fp32->bf16
    unsigned u = __builtin_bit_cast(unsigned, x);
    return (unsigned short)((u + 0x7FFFu + ((u >> 16) & 1u)) >> 16);
}

// init: clear bitmap, zero padded region counters, build W13 bf16 fragment
// table. (idx[] needs NO clearing: it is only ever read at bitmap-confirmed
// keys, all of which insert_kernel writes.) wfrag entry e = (ks*4+nt)*64+lane,
// elem j = bf16(W13[ks*32+(lane>>4)*8+j][nt*16+(lane&15)]).
__global__ void init_kernel(unsigned* __restrict__ bitmap, int nbwords,
                            unsigned* __restrict__ cnts,
                            const float* __restrict__ weight,
                            unsigned short* __restrict__ wfrag) {
    int i = blockIdx.x * blockDim.x + threadIdx.x;
    if (i < nbwords) bitmap[i] = 0u;
    if (i < 512) {
        cnts[i] = 0u;   // covers NREGION*CPAD = 432 padded counters
        const int lane = i & 63, nt = (i >> 6) & 3, ks = i >> 8;
        const float* __restrict__ w13 = weight + 13 * 4096;
        #pragma unroll
        for (int j = 0; j < 8; ++j) {
            const int k = ks * 32 + (lane >> 4) * 8 + j;
            const int n = nt * 16 + (lane & 15);
            wfrag[(size_t)i * 8 + j] = f2bf(w13[k * 64 + n]);
        }
    }
}

// set patch-bitmap bit + direct-index store (keys unique -> plain store).
__global__ void insert_kernel(const int4* __restrict__ coords, int n,
                              unsigned* __restrict__ idx,
                              unsigned* __restrict__ bitmap) {
    int i = blockIdx.x * blockDim.x + threadIdx.x;
    if (i >= n) return;
    const int4 c = coords[i];   // (b, x, y, z)
    const unsigned key = ((unsigned)c.x << 24) | ((unsigned)c.y << 16) |
                         ((unsigned)c.z << 8) | (unsigned)c.w;
    const unsigned w = ((((unsigned)c.x << 8) | (unsigned)c.y) << 11) |
                       (((unsigned)c.z >> 2) << 5) | ((unsigned)c.w >> 3);
    const unsigned bit = (((unsigned)c.z & 3u) << 3) | ((unsigned)c.w & 7u);
    atomicOr(&bitmap[w], 1u << bit);
    idx[key] = (unsigned)i;
}

// One thread per site. Patch-word existence test: word (b,x,yt,zt) holds a
// 4y x 8z occupancy tile (bit = (y&3)*8 + (z&7)). The 13 symmetric offsets
// k<13 need 5 rows: A=(x-1,y-1) B=(x-1,y) C=(x-1,y+1) [tri over z+-1],
// D=(x,y-1) [tri], E=(x,y) [z-1 bit only]. Common case: 2 loads; tile-edge
// cases add exec-masked loads; out-of-volume tiles simply aren't loaded.
// Hit resolution: batched exec-masked idx[] loads (static unroll — one
// latency round-trip for all of a wave's hits), then emit (site,k,nbi) AND
// mirror (nbi,26-k,site) into LDS; flush bucketed by tap k.
__global__ __launch_bounds__(512) void probe_pairs_kernel(
    const int4* __restrict__ coords, int n,
    const unsigned* __restrict__ idx, const unsigned* __restrict__ bitmap,
    unsigned* __restrict__ cnts, uint2* __restrict__ pairs, unsigned rcap)
{
    __shared__ unsigned lcnt;
    __shared__ unsigned lk[32], lkb[32], lkp[32];
    __shared__ uint2 lbuf[LCAP];
    if (threadIdx.x == 0) lcnt = 0u;
    if (threadIdx.x < 32) lk[threadIdx.x] = 0u;
    __syncthreads();

    const int site = blockIdx.x * blockDim.x + threadIdx.x;
    if (site < n) {
        const int4 c = coords[site];   // (b, x, y, z)
        const int b = c.x, x = c.y, y = c.z, z = c.w;
        const int r = y & 3, yt = y >> 2;
        const int s = z & 7, zt = z >> 3;
        const bool redge = (r == 0) || (r == 3);
        const int yta = (r == 0) ? yt - 1 : yt + 1;   // aux y-tile
        const bool vya = (r == 0) ? (y > 0) : (y < 255);
        const bool zl = (s == 0) && (z > 0);          // need z-1 from prev tile
        const bool zh = (s == 7) && (z < 255);        // need z+1 from next tile
        const bool vxm = (x > 0);
        const int xm = x - 1;

        #define BWORD(xx, ytt, ztt) \
            bitmap[((((unsigned)b << 8) | (unsigned)(xx)) << 11) | \
                   ((unsigned)(ytt) << 5) | (unsigned)(ztt)]

        // phase 1: all patch words in flight (independent loads)
        const unsigned Pm  = vxm ? BWORD(xm, yt, zt) : 0u;
        const unsigned Pa  = (vxm && redge && vya) ? BWORD(xm, yta, zt) : 0u;
        const unsigned Pml = (vxm && zl) ? BWORD(xm, yt, zt - 1) : 0u;
        const unsigned Pal = (vxm && redge && vya && zl)
                                 ? BWORD(xm, yta, zt - 1) : 0u;
        const unsigned Pmh = (vxm && zh) ? BWORD(xm, yt, zt + 1) : 0u;
        const unsigned Pah = (vxm && redge && vya && zh)
                                 ? BWORD(xm, yta, zt + 1) : 0u;
        const unsigned Qm  = BWORD(x, yt, zt);
        const bool qa = (r == 0) && (y > 0);
        const unsigned Qa  = qa ? BWORD(x, yt - 1, zt) : 0u;
        const unsigned Qml = zl ? BWORD(x, yt, zt - 1) : 0u;
        const unsigned Qal = (qa && zl) ? BWORD(x, yt - 1, zt - 1) : 0u;
        const unsigned Qmh = zh ? BWORD(x, yt, zt + 1) : 0u;
        const unsigned Qah = (qa && zh) ? BWORD(x, yt - 1, zt + 1) : 0u;
        #undef BWORD

        // phase 2: assemble 5 tri/bit masks
        const int rm1 = (r == 0) ? 3 : r - 1;    // byte idx of row y-1
        const int rp1 = (r == 3) ? 0 : r + 1;    // byte idx of row y+1
        const unsigned PA  = (r == 0) ? Pa : Pm;
        const unsigned PAl = (r == 0) ? Pal : Pml;
        const unsigned PAh = (r == 0) ? Pah : Pmh;
        const unsigned PC  = (r == 3) ? Pa : Pm;
        const unsigned PCl = (r == 3) ? Pal : Pml;
        const unsigned PCh = (r == 3) ? Pah : Pmh;
        const unsigned QA  = (r == 0) ? Qa : Qm;
        const unsigned QAl = (r == 0) ? Qal : Qml;
        const unsigned QAh = (r == 0) ? Qah : Qmh;

        #define ROWB(W, rr) (((W) >> ((rr) * 8)) & 0xFFu)
        unsigned triA, triB, triC, triD, bitE;
        {
            const unsigned cA = ROWB(PA, rm1), cB = ROWB(Pm, r),
                           cC = ROWB(PC, rp1), cD = ROWB(QA, rm1),
                           cE = ROWB(Qm, r);
            if (s == 0) {
                triA = ((cA & 3u) << 1) | (ROWB(PAl, rm1) >> 7);
                triB = ((cB & 3u) << 1) | (ROWB(Pml, r)   >> 7);
                triC = ((cC & 3u) << 1) | (ROWB(PCl, rp1) >> 7);
                triD = ((cD & 3u) << 1) | (ROWB(QAl, rm1) >> 7);
                bitE = ROWB(Qml, r) >> 7;
            } else if (s == 7) {
                triA = ((cA >> 6) & 3u) | ((ROWB(PAh, rm1) & 1u) << 2);
                triB = ((cB >> 6) & 3u) | ((ROWB(Pmh, r)   & 1u) << 2);
                triC = ((cC >> 6) & 3u) | ((ROWB(PCh, rp1) & 1u) << 2);
                triD = ((cD >> 6) & 3u) | ((ROWB(QAh, rm1) & 1u) << 2);
                bitE = (cE >> 6) & 1u;
            } else {
                triA = (cA >> (s - 1)) & 7u;
                triB = (cB >> (s - 1)) & 7u;
                triC = (cC >> (s - 1)) & 7u;
                triD = (cD >> (s - 1)) & 7u;
                bitE = (cE >> (s - 1)) & 1u;
            }
        }
        #undef ROWB
        const unsigned hitm = triA | (triB << 3) | (triC << 6) | (triD << 9) |
                              (bitE << 12);

        // phase 3: batched hit resolution (bit bb <-> tap k=bb; g=bb/3,
        // d=bb%3, offset (dx,dy,dz)=(g<3?-1:0, g<3?g-1:(g==3?-1:0), d-1)).
        if (hitm) {
            const unsigned skey = ((unsigned)b << 24) | ((unsigned)x << 16) |
                                  ((unsigned)y << 8) | (unsigned)z;
            unsigned nbi[13];
            // issue all idx loads (exec-masked, independent -> one round trip)
            #pragma unroll
            for (int bb = 0; bb < 13; ++bb) {
                if (hitm & (1u << bb)) {
                    const int g = bb / 3, d = bb % 3;
                    const int dx = (g < 3) ? -1 : 0;
                    const int dy = (g < 3) ? (g - 1) : ((g == 3) ? -1 : 0);
                    const int duv = (dx << 16) + (dy << 8) + (d - 1);
                    nbi[bb] = idx[(unsigned)((int)skey + duv)];
                }
            }
            // consume (static indexing only — rule #20)
            #pragma unroll
            for (int bb = 0; bb < 13; ++bb) {
                if (hitm & (1u << bb)) {
                    const uint2 p0 = make_uint2(
                        (unsigned)site | ((unsigned)bb << 18), nbi[bb]);
                    const uint2 p1 = make_uint2(
                        nbi[bb] | ((unsigned)(26 - bb) << 18), (unsigned)site);
                    const unsigned li = atomicAdd(&lcnt, 2u);
                    if (li + 1 < (unsigned)LCAP) {   // li even, LCAP even
                        lbuf[li] = p0;
                        lbuf[li + 1] = p1;
                    } else {                          // statistically ~never
                        const unsigned g0 = atomicAdd(&cnts[bb * CPAD], 1u);
                        if (g0 < rcap) pairs[(size_t)bb * rcap + g0] = p0;
                        const unsigned g1 =
                            atomicAdd(&cnts[(26 - bb) * CPAD], 1u);
                        if (g1 < rcap)
                            pairs[(size_t)(26 - bb) * rcap + g1] = p1;
                    }
                }
            }
        }
    }

    __syncthreads();
    const unsigned nloc = lcnt < (unsigned)LCAP ? lcnt : (unsigned)LCAP;
    // per-k histogram of staged pairs
    for (unsigned i = threadIdx.x; i < nloc; i += blockDim.x)
        atomicAdd(&lk[lbuf[i].x >> 18], 1u);
    __syncthreads();
    // one padded global reservation per nonempty k
    if (threadIdx.x < NREGION) {
        const unsigned c = lk[threadIdx.x];
        lkb[threadIdx.x] = c ? atomicAdd(&cnts[threadIdx.x * CPAD], c) : 0u;
        lkp[threadIdx.x] = 0u;
    }
    __syncthreads();
    // scatter into per-k regions
    for (unsigned i = threadIdx.x; i < nloc; i += blockDim.x) {
        const uint2 e = lbuf[i];
        const unsigned kk = e.x >> 18;
        const unsigned pos = atomicAdd(&lkp[kk], 1u);
        const unsigned idxp = lkb[kk] + pos;
        if (idxp < rcap) pairs[(size_t)kk * rcap + idxp] = e;
    }
}

// Dense center GEMM via MFMA: out = bias + feats @ W13.
// One wave per 16 sites x 64 oc. A: row=lane&15, k=(lane>>4)*8+j (+ks*32).
// B pre-packed in wfrag. C/D: col=lane&15, row=(lane>>4)*4+reg.
__global__ __launch_bounds__(256) void conv_center_mfma(
    const float* __restrict__ feats, const unsigned short* __restrict__ wfrag,
    const float* __restrict__ bias, float* __restrict__ out, int n)
{
    const int lane = threadIdx.x & 63;
    const int wid = blockIdx.x * (blockDim.x >> 6) + (threadIdx.x >> 6);
    const int s0 = wid * 16;
    if (s0 >= n) return;

    // B fragments: 2 ksteps x 4 ntiles, 16B per lane each
    bf16x8 bfrag[2][4];
    #pragma unroll
    for (int ks = 0; ks < 2; ++ks)
        #pragma unroll
        for (int nt = 0; nt < 4; ++nt)
            bfrag[ks][nt] = *reinterpret_cast<const bf16x8*>(
                wfrag + ((size_t)((ks * 4 + nt) * 64 + lane)) * 8);

    const int arow = s0 + (lane & 15);
    const bool vrow = arow < n;
    const float* __restrict__ fbase =
        feats + (size_t)(vrow ? arow : 0) * 64 + (lane >> 4) * 8;

    f32x4 acc[4] = {{0.f, 0.f, 0.f, 0.f}, {0.f, 0.f, 0.f, 0.f},
                    {0.f, 0.f, 0.f, 0.f}, {0.f, 0.f, 0.f, 0.f}};

    #pragma unroll
    for (int ks = 0; ks < 2; ++ks) {
        const f32x4 flo = *reinterpret_cast<const f32x4*>(fbase + ks * 32);
        const f32x4 fhi = *reinterpret_cast<const f32x4*>(fbase + ks * 32 + 4);
        bf16x8 afrag;
        afrag[0] = (short)f2bf(flo.x); afrag[1] = (short)f2bf(flo.y);
        afrag[2] = (short)f2bf(flo.z); afrag[3] = (short)f2bf(flo.w);
        afrag[4] = (short)f2bf(fhi.x); afrag[5] = (short)f2bf(fhi.y);
        afrag[6] = (short)f2bf(fhi.z); afrag[7] = (short)f2bf(fhi.w);
        #pragma unroll
        for (int nt = 0; nt < 4; ++nt)
            acc[nt] = __builtin_amdgcn_mfma_f32_16x16x32_bf16(
                afrag, bfrag[ks][nt], acc[nt], 0, 0, 0);
    }

    const int crow0 = s0 + (lane >> 4) * 4;
    const int col = lane & 15;
    #pragma unroll
    for (int nt = 0; nt < 4; ++nt) {
        const float bv = bias[nt * 16 + col];
        #pragma unroll
        for (int r = 0; r < 4; ++r) {
            const int sr = crow0 + r;
            if (sr < n)
                out[(size_t)sr * 64 + nt * 16 + col] = acc[nt][r] + bv;
        }
    }
}

// 48 blocks per tap region; one wave per pair (grid-stride within region).
// All waves of a block stream the same 16KB W[k] -> L1-resident after the
// first pair. fp32 FMA + atomics (bit-identical math to R0's pairs path).
__global__ __launch_bounds__(256) void conv_pairs_kernel(
    const float* __restrict__ feats, const float* __restrict__ weight,
    const uint2* __restrict__ pairs, const unsigned* __restrict__ cnts,
    unsigned rcap, float* __restrict__ out)
{
    const int lane = threadIdx.x & 63;
    int r = blockIdx.x / PB;
    r += (r >= 13);                     // taps 0..12,14..26
    unsigned cnt = cnts[r * CPAD];
    if (cnt > rcap) cnt = rcap;
    if (cnt == 0) return;
    const uint2* __restrict__ rp = pairs + (size_t)r * rcap;
    const float* __restrict__ wk = weight + (size_t)r * 4096;
    const unsigned wloc = (blockIdx.x % PB) * 4 + (threadIdx.x >> 6);
    for (unsigned p = wloc; p < cnt; p += (unsigned)(PB * 4)) {
        const uint2 pr = rp[p];
        const unsigned site = pr.x & 0x3FFFFu;
        const unsigned nbi = pr.y;
        const float4* __restrict__ fr =
            reinterpret_cast<const float4*>(feats + (size_t)nbi * 64);
        float a0 = 0.f, a1 = 0.f, a2 = 0.f, a3 = 0.f;
        #pragma unroll
        for (int q = 0; q < 16; ++q) {
            const float4 f = fr[q];
            a0 = fmaf(f.x, wk[(4 * q + 0) * 64 + lane], a0);
            a1 = fmaf(f.y, wk[(4 * q + 1) * 64 + lane], a1);
            a2 = fmaf(f.z, wk[(4 * q + 2) * 64 + lane], a2);
            a3 = fmaf(f.w, wk[(4 * q + 3) * 64 + lane], a3);
        }
        atomicAdd(&out[(size_t)site * 64 + lane], (a0 + a1) + (a2 + a3));
    }
}

extern "C" void kernel_launch(void* const* d_in, const int* in_sizes, int n_in,
                              void* d_out, int out_size, void* d_ws, size_t ws_size,
                              hipStream_t stream) {
    const float* feats  = (const float*)d_in[0];   // (N, 64)
    const int4*  coords = (const int4*)d_in[1];    // (N, 4)
    const float* weight = (const float*)d_in[2];   // (27, 64, 64)
    const float* bias   = (const float*)d_in[3];   // (64,)
    float* out = (float*)d_out;

    const int n = in_sizes[1] / 4;

    // ws layout: bitmap (1M u32 = 4MB) | cnts (2KB) | wfrag (8KB) |
    //            idx (32M u32 = 128MB, never cleared) | pairs (27 x rcap)
    unsigned* bitmap = (unsigned*)d_ws;
    unsigned* cnts = bitmap + NBWORDS;
    unsigned short* wfrag = (unsigned short*)((char*)cnts + 2048);
    unsigned* idxarr = (unsigned*)((char*)wfrag + 8192);
    uint2* pairs = (uint2*)(idxarr + NVOX);
    const size_t used = (size_t)NBWORDS * 4 + 2048 + 8192 + NVOX * 4;
    size_t cap_sz = (ws_size > used) ? (ws_size - used) / sizeof(uint2) : 0;
    if (cap_sz > (size_t)(4 << 20)) cap_sz = (size_t)(4 << 20);
    const unsigned rcap = (unsigned)(cap_sz / NREGION);

    {
        int blocks = (NBWORDS + 255) / 256;
        init_kernel<<<blocks, 256, 0, stream>>>(bitmap, NBWORDS, cnts,
                                                weight, wfrag);
    }
    {
        int blocks = (n + 255) / 256;
        insert_kernel<<<blocks, 256, 0, stream>>>(coords, n, idxarr, bitmap);
    }
    {
        int blocks = (n + 511) / 512;   // 512 sites/block, 1 thread/site
        probe_pairs_kernel<<<blocks, 512, 0, stream>>>(coords, n, idxarr,
                                                       bitmap, cnts, pairs,
                                                       rcap);
    }
    {
        int waves = (n + 15) / 16;
        int blocks = (waves + 3) / 4;
        conv_center_mfma<<<blocks, 256, 0, stream>>>(feats, wfrag, bias, out, n);
    }
    {
        conv_pairs_kernel<<<26 * PB, 256, 0, stream>>>(feats, weight, pairs,
                                                       cnts, rcap, out);
    }
}